// Round 1
// baseline (60.901 us; speedup 1.0000x reference)
//
#include <hip/hip_runtime.h>

// ConstrainNet forward:
//   out[0:64]        = V[0, :64] - x0
//   out[t*64 + s]    = dot(AB[s,:], V[t-1,:]) - V[t, s]   for t = 1..T-1
// where AB = [A | B] (64 x 96), V = net_input.reshape(T, 96).
//
// Sizes fixed by setup_inputs(): n_state=64, n_input=32, n_all=96, T=128.
// Tiny problem (~1.5 MFLOP, ~100 KB) -> single launch, one block per
// timestep, one thread per output state element.

#define NS 64   // n_state
#define NI 32   // n_input
#define NA 96   // n_all

__global__ __launch_bounds__(64) void constrainnet_kernel(
    const float* __restrict__ A,
    const float* __restrict__ B,
    const float* __restrict__ x0,
    const float* __restrict__ V,   // (T, NA) row-major
    float* __restrict__ out)       // (T, NS) row-major
{
    const int t = blockIdx.x;
    const int s = threadIdx.x;     // 0..63

    if (t == 0) {
        // row-block 0: I @ v0[:NS] - x0
        out[s] = V[s] - x0[s];
        return;   // uniform over the (single-wave) block — safe
    }

    // Stage V[t-1, :] (96 floats) into LDS; reads below are same-address
    // broadcasts (conflict-free).
    __shared__ float sV[NA];
    const float* vprev = V + (size_t)(t - 1) * NA;
    sV[s] = vprev[s];
    if (s < NA - NS) sV[NS + s] = vprev[NS + s];
    __syncthreads();

    float acc = 0.f;

    // A row s: 64 floats, 256 B-aligned -> 16 float4 loads per lane.
    const float4* a4 = (const float4*)(A + (size_t)s * NS);
    #pragma unroll
    for (int i = 0; i < NS / 4; ++i) {
        float4 av = a4[i];
        acc += av.x * sV[4 * i + 0];
        acc += av.y * sV[4 * i + 1];
        acc += av.z * sV[4 * i + 2];
        acc += av.w * sV[4 * i + 3];
    }

    // B row s: 32 floats, 128 B-aligned -> 8 float4 loads per lane.
    const float4* b4 = (const float4*)(B + (size_t)s * NI);
    #pragma unroll
    for (int i = 0; i < NI / 4; ++i) {
        float4 bv = b4[i];
        acc += bv.x * sV[NS + 4 * i + 0];
        acc += bv.y * sV[NS + 4 * i + 1];
        acc += bv.z * sV[NS + 4 * i + 2];
        acc += bv.w * sV[NS + 4 * i + 3];
    }

    // out_rest: prop - V[t, :NS]; this read is lane-coalesced.
    out[(size_t)t * NS + s] = acc - V[(size_t)t * NA + s];
}

extern "C" void kernel_launch(void* const* d_in, const int* in_sizes, int n_in,
                              void* d_out, int out_size, void* d_ws, size_t ws_size,
                              hipStream_t stream) {
    const float* A  = (const float*)d_in[0];
    const float* B  = (const float*)d_in[1];
    const float* x0 = (const float*)d_in[2];
    const float* V  = (const float*)d_in[3];
    float* out = (float*)d_out;

    // T is a device-side scalar input; recover it from flat sizes instead.
    const int T = in_sizes[3] / NA;   // 12288 / 96 = 128

    constrainnet_kernel<<<T, 64, 0, stream>>>(A, B, x0, V, out);
}